// Round 1
// baseline (7003.622 us; speedup 1.0000x reference)
//
#include <hip/hip_runtime.h>
#include <math.h>

#define Bn 64
#define Pn 512
#define Dn 49
#define Hn 8
#define Ln 6
#define HDn 392   // Hn*Dn

static __device__ __forceinline__ float inv_scale() { return 1.0f / 7.000001f; }

// ---------------- prep: Weff[l,h,o2,o] = sum_d Wh[l,h,d,o] * Wout[l,o2,h*49+d]
//                  beff[l,o2] = sum_{h,d} bh[l,h,d] * Wout[l,o2,h*49+d]
__global__ void prep_weff_kernel(const float* __restrict__ Wh,
                                 const float* __restrict__ bh,
                                 const float* __restrict__ Wout,
                                 float* __restrict__ Weff,
                                 float* __restrict__ beff) {
    int idx = blockIdx.x * 256 + threadIdx.x;
    const int NW = Ln * Hn * Dn * Dn;
    if (idx < NW) {
        int o  = idx % Dn;
        int t  = idx / Dn;
        int o2 = t % Dn;  t /= Dn;
        int h  = t % Hn;
        int l  = t / Hn;
        const float* wh = Wh + ((size_t)(l * Hn + h) * Dn) * Dn;      // [d][o]
        const float* wo = Wout + ((size_t)l * Dn + o2) * HDn + h * Dn; // [d]
        float s = 0.f;
        for (int d = 0; d < Dn; ++d) s = fmaf(wh[d * Dn + o], wo[d], s);
        Weff[idx] = s;
    } else if (idx < NW + Ln * Dn) {
        int j  = idx - NW;
        int o2 = j % Dn;
        int l  = j / Dn;
        const float* wo  = Wout + ((size_t)l * Dn + o2) * HDn;
        const float* bhl = bh + (size_t)l * Hn * Dn;
        float s = 0.f;
        for (int c = 0; c < HDn; ++c) s = fmaf(bhl[c], wo[c], s);
        beff[j] = s;
    }
}

// ---------------- QKV projection: one block = 256 rows for one (h, mat)
__global__ __launch_bounds__(256)
void qkv_kernel(const float* __restrict__ xin,   // [B,P,D] (full tensor)
                const float* __restrict__ Wq, const float* __restrict__ bq,
                const float* __restrict__ Wk, const float* __restrict__ bk,
                const float* __restrict__ Wv, const float* __restrict__ bv,
                float* __restrict__ Qo, float* __restrict__ Ko, float* __restrict__ Vo, // [Bc,H,P,D]
                int b_off) {
    __shared__ float lx[256 * Dn];
    __shared__ float lw[Dn * 52];
    __shared__ float lb[Dn];
    const int tid = threadIdx.x;
    const int h   = blockIdx.y;
    const int mat = blockIdx.z;
    const float* W    = (mat == 0) ? Wq : (mat == 1) ? Wk : Wv;
    const float* bias = (mat == 0) ? bq : (mat == 1) ? bk : bv;
    float* out        = (mat == 0) ? Qo : (mat == 1) ? Ko : Vo;

    const int r0 = blockIdx.x * 256;  // chunk-local flat row (b_local*P + p)
    const float* xsrc = xin + ((size_t)b_off * Pn + r0) * Dn;
    for (int t = tid; t < 256 * Dn; t += 256) lx[t] = xsrc[t];
    const float* Wh_ = W + (size_t)h * Dn * Dn;
    for (int t = tid; t < Dn * Dn; t += 256) lw[(t / Dn) * 52 + (t % Dn)] = Wh_[t];
    if (tid < Dn) lb[tid] = bias[h * Dn + tid];
    __syncthreads();

    float xr[Dn];
    #pragma unroll
    for (int i = 0; i < Dn; ++i) xr[i] = lx[tid * Dn + i];

    const int rr = r0 + tid;
    const int bl = rr >> 9;        // / Pn
    const int p  = rr & (Pn - 1);
    float* orow = out + (((size_t)bl * Hn + h) * Pn + p) * Dn;
    for (int o = 0; o < Dn; ++o) {
        float acc = lb[o];
        const float* wrow = &lw[o * 52];
        #pragma unroll
        for (int i = 0; i < Dn; ++i) acc = fmaf(xr[i], wrow[i], acc);
        orow[o] = acc;
    }
}

// ---------------- attention: block = 128 query rows of one (b,h); fixed-max softmax
__global__ __launch_bounds__(128)
void attn_kernel(const float* __restrict__ Q, const float* __restrict__ K,
                 const float* __restrict__ V, float* __restrict__ AO) {
    __shared__ float lk[64 * 52];
    __shared__ float lv[64 * 52];
    const int tid = threadIdx.x;
    const int h   = blockIdx.y;
    const int bl  = blockIdx.z;
    const int p   = blockIdx.x * 128 + tid;
    const size_t bh = ((size_t)bl * Hn + h) * Pn;

    float qr[Dn];
    const float* qrow = Q + (bh + p) * Dn;
    #pragma unroll
    for (int i = 0; i < Dn; ++i) qr[i] = qrow[i];
    float acc[Dn];
    #pragma unroll
    for (int i = 0; i < Dn; ++i) acc[i] = 0.f;
    float lsum = 0.f;

    for (int kt = 0; kt < Pn / 64; ++kt) {
        const float* ksrc = K + (bh + kt * 64) * Dn;
        const float* vsrc = V + (bh + kt * 64) * Dn;
        for (int t = tid; t < 64 * Dn; t += 128) {
            int r = t / Dn, c = t - r * Dn;
            lk[r * 52 + c] = ksrc[t];
            lv[r * 52 + c] = vsrc[t];
        }
        __syncthreads();
        for (int k = 0; k < 64; ++k) {
            const float* kr = &lk[k * 52];
            float s = 0.f;
            #pragma unroll
            for (int i = 0; i < Dn; ++i) s = fmaf(qr[i], kr[i], s);
            s *= inv_scale();
            s = fminf(fmaxf(s, -30.f), 30.f);
            float pw = __expf(s - 30.f);   // clip => max is 30, no online max needed
            lsum += pw;
            const float* vr = &lv[k * 52];
            #pragma unroll
            for (int i = 0; i < Dn; ++i) acc[i] = fmaf(pw, vr[i], acc[i]);
        }
        __syncthreads();
    }
    const float inv = 1.0f / lsum;
    float* orow = AO + (bh + p) * Dn;
    #pragma unroll
    for (int i = 0; i < Dn; ++i) orow[i] = acc[i] * inv;
}

// ---------------- fused head-proj + concat + out-proj via Weff
__global__ __launch_bounds__(256)
void outproj_kernel(const float* __restrict__ AO,     // [Bc,H,P,D]
                    const float* __restrict__ Weff,   // layer base [H,D,D]
                    const float* __restrict__ beff,   // layer base [D]
                    float* __restrict__ xout,         // [B,P,D] full
                    int b_off) {
    __shared__ float la[256 * Dn];
    __shared__ float lw[Dn * 52];
    const int tid = threadIdx.x;
    const int r0  = blockIdx.x * 256;
    const int bl  = r0 >> 9;
    const int p0  = r0 & (Pn - 1);

    float acc[Dn];
    #pragma unroll
    for (int o = 0; o < Dn; ++o) acc[o] = beff[o];

    for (int h = 0; h < Hn; ++h) {
        const float* asrc = AO + (((size_t)bl * Hn + h) * Pn + p0) * Dn;
        for (int t = tid; t < 256 * Dn; t += 256) la[t] = asrc[t];
        const float* wsrc = Weff + (size_t)h * Dn * Dn;
        for (int t = tid; t < Dn * Dn; t += 256) lw[(t / Dn) * 52 + (t % Dn)] = wsrc[t];
        __syncthreads();
        float ar[Dn];
        #pragma unroll
        for (int i = 0; i < Dn; ++i) ar[i] = la[tid * Dn + i];
        for (int o = 0; o < Dn; ++o) {
            const float* wrow = &lw[o * 52];
            float s = acc[o];
            #pragma unroll
            for (int i = 0; i < Dn; ++i) s = fmaf(ar[i], wrow[i], s);
            acc[o] = s;
        }
        __syncthreads();
    }
    const int rr = r0 + tid;
    const int gb = b_off + (rr >> 9);
    const int p  = rr & (Pn - 1);
    float* orow = xout + ((size_t)gb * Pn + p) * Dn;
    #pragma unroll
    for (int o = 0; o < Dn; ++o) orow[o] = acc[o];
}

// ---------------- mean-pool over P
__global__ __launch_bounds__(64)
void pool_kernel(const float* __restrict__ x, float* __restrict__ pooled) {
    const int b = blockIdx.x, d = threadIdx.x;
    if (d >= Dn) return;
    float s = 0.f;
    const float* xb = x + (size_t)b * Pn * Dn + d;
    for (int p = 0; p < Pn; ++p) s += xb[p * Dn];
    pooled[b * Dn + d] = s * (1.0f / Pn);
}

// ---------------- MLP + log-softmax + NLL (one wave; one thread per batch elem)
__global__ __launch_bounds__(64)
void head_kernel(const float* __restrict__ pooled, const int* __restrict__ labels,
                 const float* __restrict__ W1, const float* __restrict__ b1,
                 const float* __restrict__ W2, const float* __restrict__ b2,
                 float* __restrict__ out) {
    __shared__ float lloss[64];
    const int b = threadIdx.x;
    float pr[Dn];
    #pragma unroll
    for (int i = 0; i < Dn; ++i) pr[i] = pooled[b * Dn + i];
    float hh[25];
    for (int j = 0; j < 25; ++j) {
        float s = b1[j];
        for (int i = 0; i < Dn; ++i) s = fmaf(pr[i], W1[j * Dn + i], s);
        hh[j] = fmaxf(s, 0.f);
    }
    float lg[10];
    float m = -1e30f;
    for (int k = 0; k < 10; ++k) {
        float s = b2[k];
        for (int j = 0; j < 25; ++j) s = fmaf(hh[j], W2[k * 25 + j], s);
        lg[k] = s;
        m = fmaxf(m, s);
    }
    float se = 0.f;
    for (int k = 0; k < 10; ++k) se += __expf(lg[k] - m);
    float lse = m + __logf(se);
    int lbl = labels[b];
    lloss[b] = lse - lg[lbl];
    __syncthreads();
    if (b == 0) {
        float s = 0.f;
        for (int i = 0; i < 64; ++i) s += lloss[i];
        out[0] = s * (1.0f / 64.0f);
    }
}

extern "C" void kernel_launch(void* const* d_in, const int* in_sizes, int n_in,
                              void* d_out, int out_size, void* d_ws, size_t ws_size,
                              hipStream_t stream) {
    const float* emb    = (const float*)d_in[0];
    const int*   labels = (const int*)d_in[1];
    const float* Wq = (const float*)d_in[2];
    const float* bq = (const float*)d_in[3];
    const float* Wk = (const float*)d_in[4];
    const float* bk = (const float*)d_in[5];
    const float* Wv = (const float*)d_in[6];
    const float* bv = (const float*)d_in[7];
    const float* Wh = (const float*)d_in[8];
    const float* bh = (const float*)d_in[9];
    const float* Wout = (const float*)d_in[10];
    const float* W1 = (const float*)d_in[11];
    const float* b1 = (const float*)d_in[12];
    const float* W2 = (const float*)d_in[13];
    const float* b2 = (const float*)d_in[14];
    float* out = (float*)d_out;

    float* ws = (float*)d_ws;
    size_t off = 0;
    auto alloc = [&](size_t n) { float* pp = ws + off; off += n; return pp; };

    float* Weff   = alloc((size_t)Ln * Hn * Dn * Dn);
    float* beff   = alloc((size_t)Ln * Dn);
    float* x1     = alloc((size_t)Bn * Pn * Dn);
    float* x2     = alloc((size_t)Bn * Pn * Dn);
    float* pooled = alloc((size_t)Bn * Dn);

    const size_t HPD = (size_t)Hn * Pn * Dn;
    size_t avail = ws_size / sizeof(float);
    size_t remain = (avail > off) ? (avail - off) : 0;
    int Bc = Bn;
    while (Bc > 1 && 4ull * (size_t)Bc * HPD > remain) Bc >>= 1;

    float* Qb  = alloc((size_t)Bc * HPD);
    float* Kb  = alloc((size_t)Bc * HPD);
    float* Vb  = alloc((size_t)Bc * HPD);
    float* AOb = alloc((size_t)Bc * HPD);

    // precompute fused head+out projection weights
    {
        int total = Ln * Hn * Dn * Dn + Ln * Dn;
        int g = (total + 255) / 256;
        prep_weff_kernel<<<g, 256, 0, stream>>>(Wh, bh, Wout, Weff, beff);
    }

    float* xs[2] = {x1, x2};
    for (int l = 0; l < Ln; ++l) {
        const float* xin = (l == 0) ? emb : xs[(l + 1) & 1];
        float* xout = xs[l & 1];
        const float* Wq_l = Wq + (size_t)l * Hn * Dn * Dn;
        const float* Wk_l = Wk + (size_t)l * Hn * Dn * Dn;
        const float* Wv_l = Wv + (size_t)l * Hn * Dn * Dn;
        const float* bq_l = bq + (size_t)l * Hn * Dn;
        const float* bk_l = bk + (size_t)l * Hn * Dn;
        const float* bv_l = bv + (size_t)l * Hn * Dn;
        const float* We_l = Weff + (size_t)l * Hn * Dn * Dn;
        const float* be_l = beff + (size_t)l * Dn;

        for (int b0 = 0; b0 < Bn; b0 += Bc) {
            dim3 g1(Bc * Pn / 256, Hn, 3);
            qkv_kernel<<<g1, 256, 0, stream>>>(xin, Wq_l, bq_l, Wk_l, bk_l, Wv_l, bv_l,
                                               Qb, Kb, Vb, b0);
            dim3 g2(Pn / 128, Hn, Bc);
            attn_kernel<<<g2, 128, 0, stream>>>(Qb, Kb, Vb, AOb);
            dim3 g3(Bc * Pn / 256);
            outproj_kernel<<<g3, 256, 0, stream>>>(AOb, We_l, be_l, xout, b0);
        }
    }

    pool_kernel<<<Bn, 64, 0, stream>>>(xs[1], pooled);  // final x is xs[(Ln-1)&1] = xs[1]
    head_kernel<<<1, 64, 0, stream>>>(pooled, labels, W1, b1, W2, b2, out);
}

// Round 2
// 2377.630 us; speedup vs baseline: 2.9456x; 2.9456x over previous
//
#include <hip/hip_runtime.h>
#include <hip/hip_bf16.h>
#include <math.h>

#define Bn 64
#define Pn 512
#define Dn 49
#define Hn 8
#define Ln 6
#define HDn 392   // Hn*Dn

typedef __bf16 bf16x8 __attribute__((ext_vector_type(8)));
typedef float f32x4 __attribute__((ext_vector_type(4)));

static __device__ __forceinline__ float inv_scale() { return 1.0f / 7.000001f; }

static __device__ __forceinline__ unsigned short f2bf(float f) {
    return __builtin_bit_cast(unsigned short, __float2bfloat16(f));
}

// ---------------- prep: Weff[l,h,o2,o] = sum_d Wh[l,h,d,o] * Wout[l,o2,h*49+d]
__global__ void prep_weff_kernel(const float* __restrict__ Wh,
                                 const float* __restrict__ bh,
                                 const float* __restrict__ Wout,
                                 float* __restrict__ Weff,
                                 float* __restrict__ beff) {
    int idx = blockIdx.x * 256 + threadIdx.x;
    const int NW = Ln * Hn * Dn * Dn;
    if (idx < NW) {
        int o  = idx % Dn;
        int t  = idx / Dn;
        int o2 = t % Dn;  t /= Dn;
        int h  = t % Hn;
        int l  = t / Hn;
        const float* wh = Wh + ((size_t)(l * Hn + h) * Dn) * Dn;      // [d][o]
        const float* wo = Wout + ((size_t)l * Dn + o2) * HDn + h * Dn; // [d]
        float s = 0.f;
        for (int d = 0; d < Dn; ++d) s = fmaf(wh[d * Dn + o], wo[d], s);
        Weff[idx] = s;
    } else if (idx < NW + Ln * Dn) {
        int j  = idx - NW;
        int o2 = j % Dn;
        int l  = j / Dn;
        const float* wo  = Wout + ((size_t)l * Dn + o2) * HDn;
        const float* bhl = bh + (size_t)l * Hn * Dn;
        float s = 0.f;
        for (int c = 0; c < HDn; ++c) s = fmaf(bhl[c], wo[c], s);
        beff[j] = s;
    }
}

// ---------------- QKV projection -> bf16 outputs (Q,K padded D=64; V transposed [d][p])
__global__ __launch_bounds__(256)
void qkv_kernel(const float* __restrict__ xin,
                const float* __restrict__ Wq, const float* __restrict__ bq,
                const float* __restrict__ Wk, const float* __restrict__ bk,
                const float* __restrict__ Wv, const float* __restrict__ bv,
                unsigned short* __restrict__ Qb, unsigned short* __restrict__ Kb,
                unsigned short* __restrict__ Vt, int b_off) {
    __shared__ float lw[49 * 52];
    __shared__ float lb[64];
    __shared__ uint4 ltv[2048];           // 32 KiB bf16 tile
    char* lt = (char*)ltv;
    const int tid = threadIdx.x;
    const int h   = blockIdx.y;
    const int mat = blockIdx.z;
    const float* W    = (mat == 0) ? Wq : (mat == 1) ? Wk : Wv;
    const float* bias = (mat == 0) ? bq : (mat == 1) ? bk : bv;

    for (int t = tid; t < 49 * 49; t += 256) lw[(t / 49) * 52 + (t % 49)] = W[(size_t)h * 2401 + t];
    if (tid < 49) lb[tid] = bias[h * 49 + tid];
    {
        uint4 z = {0, 0, 0, 0};
        #pragma unroll
        for (int k = 0; k < 8; ++k) ltv[k * 256 + tid] = z;
    }
    __syncthreads();

    const int r0 = blockIdx.x * 256;
    const float* xp = xin + ((size_t)b_off * Pn + r0 + tid) * Dn;
    float xr[49];
    #pragma unroll
    for (int i = 0; i < 49; ++i) xr[i] = xp[i];

    if (mat < 2) {
        // rows: lt[row=tid][col=o] bf16, XOR-swizzled 16B slots within each 128B row
        #pragma unroll 1
        for (int op = 0; op < 24; ++op) {
            const float* w0 = &lw[(2 * op) * 52];
            const float* w1 = &lw[(2 * op + 1) * 52];
            float a0 = lb[2 * op], a1 = lb[2 * op + 1];
            #pragma unroll
            for (int i = 0; i < 49; ++i) { a0 = fmaf(xr[i], w0[i], a0); a1 = fmaf(xr[i], w1[i], a1); }
            unsigned int pk = (unsigned int)f2bf(a0) | ((unsigned int)f2bf(a1) << 16);
            *(unsigned int*)(lt + tid * 128 + ((4 * op) ^ ((tid & 7) << 4))) = pk;
        }
        {
            const float* w0 = &lw[48 * 52];
            float a0 = lb[48];
            #pragma unroll
            for (int i = 0; i < 49; ++i) a0 = fmaf(xr[i], w0[i], a0);
            *(unsigned short*)(lt + tid * 128 + (96 ^ ((tid & 7) << 4))) = f2bf(a0);
        }
    } else {
        // transposed: lt_t[d][p_local] bf16, rows of 256, linear (writes conflict-free)
        #pragma unroll 1
        for (int o = 0; o < 49; ++o) {
            const float* w0 = &lw[o * 52];
            float a0 = lb[o];
            #pragma unroll
            for (int i = 0; i < 49; ++i) a0 = fmaf(xr[i], w0[i], a0);
            *((unsigned short*)lt + o * 256 + tid) = f2bf(a0);
        }
    }
    __syncthreads();

    if (mat < 2) {
        unsigned short* out = (mat == 0) ? Qb : Kb;
        #pragma unroll
        for (int k = 0; k < 8; ++k) {
            int cid = k * 256 + tid;
            int row = cid >> 3, c8 = cid & 7;
            int rr = r0 + row;
            int bl = rr >> 9, p = rr & 511;
            uint4 v = *(uint4*)(lt + row * 128 + 16 * (c8 ^ (row & 7)));
            *(uint4*)(out + (((size_t)bl * Hn + h) * Pn + p) * 64 + c8 * 8) = v;
        }
    } else {
        const int bl = r0 >> 9, p0 = r0 & 511;
        #pragma unroll
        for (int k = 0; k < 8; ++k) {
            int cid = k * 256 + tid;
            int d = cid >> 5, j = cid & 31;
            uint4 v = *(uint4*)((unsigned short*)lt + cid * 8);
            *(uint4*)(Vt + (((size_t)bl * Hn + h) * 64 + d) * Pn + p0 + j * 8) = v;
        }
    }
}

// ---------------- MFMA attention: block = 4 waves x 16 q-rows, fixed-max softmax
__global__ __launch_bounds__(256)
void attn_mfma_kernel(const unsigned short* __restrict__ Qb,
                      const unsigned short* __restrict__ Kb,
                      const unsigned short* __restrict__ Vt,
                      float* __restrict__ AO) {
    __shared__ uint4 sbuf4[1536];                 // 24 KiB: K 8K | V 8K | P 4x2K
    char* ldsb = (char*)sbuf4;
    const int tid  = threadIdx.x;
    const int w    = tid >> 6, lane = tid & 63;
    const int g    = lane >> 4, c = lane & 15;
    const int bh   = blockIdx.z * Hn + blockIdx.y;
    const int q0   = blockIdx.x * 64;

    char* Klb = ldsb;
    char* Vlb = ldsb + 8192;
    char* Plb = ldsb + 16384 + w * 2048;

    // Q A-frags: row = lane&15, k-elems d = g*8 + dh*32 (held all kernel)
    const unsigned short* qrow = Qb + ((size_t)bh * Pn + q0 + w * 16 + c) * 64;
    bf16x8 qf0 = *(const bf16x8*)(qrow + g * 8);
    bf16x8 qf1 = *(const bf16x8*)(qrow + g * 8 + 32);

    float lsum[4] = {0.f, 0.f, 0.f, 0.f};
    f32x4 oacc[4];
    #pragma unroll
    for (int dt = 0; dt < 4; ++dt) oacc[dt] = (f32x4){0.f, 0.f, 0.f, 0.f};

    const unsigned short* Kg0 = Kb + ((size_t)bh * Pn) * 64;
    const unsigned short* Vg0 = Vt + ((size_t)bh * 64) * Pn;

    for (int kt = 0; kt < 8; ++kt) {
        // ---- stage K-tile [64][64] and V^T-tile [64 d][64 k], XOR-swizzled
        const unsigned short* Kg = Kg0 + (size_t)kt * 64 * 64;
        const unsigned short* Vg = Vg0 + kt * 64;
        #pragma unroll
        for (int i = 0; i < 2; ++i) {
            int chunk = tid + i * 256;              // 0..511
            int row = chunk >> 3, c8 = chunk & 7;
            *(uint4*)(Klb + row * 128 + 16 * (c8 ^ (row & 7))) =
                *(const uint4*)(Kg + row * 64 + c8 * 8);
            *(uint4*)(Vlb + row * 128 + 16 * (c8 ^ (row & 7))) =
                *(const uint4*)(Vg + (size_t)row * Pn + c8 * 8);
        }
        __syncthreads();

        // ---- scores: 4 tiles of 16 keys, 2 mfma each (d halves)
        #pragma unroll
        for (int t = 0; t < 4; ++t) {
            int krow = t * 16 + c;
            bf16x8 kf0 = *(const bf16x8*)(Klb + krow * 128 + 16 * ((g    ) ^ (krow & 7)));
            bf16x8 kf1 = *(const bf16x8*)(Klb + krow * 128 + 16 * ((g + 4) ^ (krow & 7)));
            f32x4 s4 = {0.f, 0.f, 0.f, 0.f};
            s4 = __builtin_amdgcn_mfma_f32_16x16x32_bf16(qf0, kf0, s4, 0, 0, 0);
            s4 = __builtin_amdgcn_mfma_f32_16x16x32_bf16(qf1, kf1, s4, 0, 0, 0);
            #pragma unroll
            for (int r = 0; r < 4; ++r) {
                float s = s4[r] * inv_scale();
                s = fminf(fmaxf(s, -30.f), 30.f);
                float p = __expf(s - 30.f);         // fixed max = 30 (post-clip)
                lsum[r] += p;
                int prow = 4 * g + r;               // q-local row
                *(unsigned short*)(Plb + prow * 128 + ((2 * (t * 16 + c)) ^ ((prow & 7) << 4))) = f2bf(p);
            }
        }
        // wave-local LDS visibility for P (cross-lane within wave)
        asm volatile("s_waitcnt lgkmcnt(0)" ::: "memory");
        __builtin_amdgcn_sched_barrier(0);

        // ---- PV: A = P (row=q-local=lane&15), B = V^T rows
        #pragma unroll
        for (int kk = 0; kk < 2; ++kk) {
            bf16x8 pa = *(const bf16x8*)(Plb + c * 128 + 16 * ((g + 4 * kk) ^ (c & 7)));
            #pragma unroll
            for (int dt = 0; dt < 4; ++dt) {
                int vrow = dt * 16 + c;
                bf16x8 vf = *(const bf16x8*)(Vlb + vrow * 128 + 16 * ((g + 4 * kk) ^ (vrow & 7)));
                oacc[dt] = __builtin_amdgcn_mfma_f32_16x16x32_bf16(pa, vf, oacc[dt], 0, 0, 0);
            }
        }
        __syncthreads();
    }

    // reduce lsum over the 16 lanes sharing g (they hold disjoint key subsets)
    float rinv[4];
    #pragma unroll
    for (int r = 0; r < 4; ++r) {
        float v = lsum[r];
        v += __shfl_xor(v, 1);
        v += __shfl_xor(v, 2);
        v += __shfl_xor(v, 4);
        v += __shfl_xor(v, 8);
        rinv[r] = 1.0f / v;
    }
    // write AO fp32 [bh][q][49]: q = q0 + w*16 + 4g + r ; d = dt*16 + c
    #pragma unroll
    for (int dt = 0; dt < 4; ++dt) {
        int d = dt * 16 + c;
        if (d < Dn) {
            #pragma unroll
            for (int r = 0; r < 4; ++r) {
                AO[((size_t)bh * Pn + q0 + w * 16 + 4 * g + r) * Dn + d] = oacc[dt][r] * rinv[r];
            }
        }
    }
}

// ---------------- fused head-proj + concat + out-proj via Weff (fp32)
__global__ __launch_bounds__(256)
void outproj_kernel(const float* __restrict__ AO,     // [Bc,H,P,D]
                    const float* __restrict__ Weff,   // layer base [H,D,D]
                    const float* __restrict__ beff,   // layer base [D]
                    float* __restrict__ xout,         // [B,P,D] full
                    int b_off) {
    __shared__ float la[256 * Dn];
    __shared__ float lw[Dn * 52];
    const int tid = threadIdx.x;
    const int r0  = blockIdx.x * 256;
    const int bl  = r0 >> 9;
    const int p0  = r0 & (Pn - 1);

    float acc[Dn];
    #pragma unroll
    for (int o = 0; o < Dn; ++o) acc[o] = beff[o];

    for (int h = 0; h < Hn; ++h) {
        const float* asrc = AO + (((size_t)bl * Hn + h) * Pn + p0) * Dn;
        for (int t = tid; t < 256 * Dn; t += 256) la[t] = asrc[t];
        const float* wsrc = Weff + (size_t)h * Dn * Dn;
        for (int t = tid; t < Dn * Dn; t += 256) lw[(t / Dn) * 52 + (t % Dn)] = wsrc[t];
        __syncthreads();
        float ar[Dn];
        #pragma unroll
        for (int i = 0; i < Dn; ++i) ar[i] = la[tid * Dn + i];
        for (int o = 0; o < Dn; ++o) {
            const float* wrow = &lw[o * 52];
            float s = acc[o];
            #pragma unroll
            for (int i = 0; i < Dn; ++i) s = fmaf(ar[i], wrow[i], s);
            acc[o] = s;
        }
        __syncthreads();
    }
    const int rr = r0 + tid;
    const int gb = b_off + (rr >> 9);
    const int p  = rr & (Pn - 1);
    float* orow = xout + ((size_t)gb * Pn + p) * Dn;
    #pragma unroll
    for (int o = 0; o < Dn; ++o) orow[o] = acc[o];
}

// ---------------- mean-pool over P
__global__ __launch_bounds__(64)
void pool_kernel(const float* __restrict__ x, float* __restrict__ pooled) {
    const int b = blockIdx.x, d = threadIdx.x;
    if (d >= Dn) return;
    float s = 0.f;
    const float* xb = x + (size_t)b * Pn * Dn + d;
    for (int p = 0; p < Pn; ++p) s += xb[p * Dn];
    pooled[b * Dn + d] = s * (1.0f / Pn);
}

// ---------------- MLP + log-softmax + NLL
__global__ __launch_bounds__(64)
void head_kernel(const float* __restrict__ pooled, const int* __restrict__ labels,
                 const float* __restrict__ W1, const float* __restrict__ b1,
                 const float* __restrict__ W2, const float* __restrict__ b2,
                 float* __restrict__ out) {
    __shared__ float lloss[64];
    const int b = threadIdx.x;
    float pr[Dn];
    #pragma unroll
    for (int i = 0; i < Dn; ++i) pr[i] = pooled[b * Dn + i];
    float hh[25];
    for (int j = 0; j < 25; ++j) {
        float s = b1[j];
        for (int i = 0; i < Dn; ++i) s = fmaf(pr[i], W1[j * Dn + i], s);
        hh[j] = fmaxf(s, 0.f);
    }
    float lg[10];
    float m = -1e30f;
    for (int k = 0; k < 10; ++k) {
        float s = b2[k];
        for (int j = 0; j < 25; ++j) s = fmaf(hh[j], W2[k * 25 + j], s);
        lg[k] = s;
        m = fmaxf(m, s);
    }
    float se = 0.f;
    for (int k = 0; k < 10; ++k) se += __expf(lg[k] - m);
    float lse = m + __logf(se);
    int lbl = labels[b];
    lloss[b] = lse - lg[lbl];
    __syncthreads();
    if (b == 0) {
        float s = 0.f;
        for (int i = 0; i < 64; ++i) s += lloss[i];
        out[0] = s * (1.0f / 64.0f);
    }
}

extern "C" void kernel_launch(void* const* d_in, const int* in_sizes, int n_in,
                              void* d_out, int out_size, void* d_ws, size_t ws_size,
                              hipStream_t stream) {
    const float* emb    = (const float*)d_in[0];
    const int*   labels = (const int*)d_in[1];
    const float* Wq = (const float*)d_in[2];
    const float* bq = (const float*)d_in[3];
    const float* Wk = (const float*)d_in[4];
    const float* bk = (const float*)d_in[5];
    const float* Wv = (const float*)d_in[6];
    const float* bv = (const float*)d_in[7];
    const float* Wh = (const float*)d_in[8];
    const float* bh = (const float*)d_in[9];
    const float* Wout = (const float*)d_in[10];
    const float* W1 = (const float*)d_in[11];
    const float* b1 = (const float*)d_in[12];
    const float* W2 = (const float*)d_in[13];
    const float* b2 = (const float*)d_in[14];
    float* out = (float*)d_out;

    char* base = (char*)d_ws;
    size_t off = 0;
    auto alloc = [&](size_t bytes) {
        off = (off + 255) & ~(size_t)255;
        char* p = base + off;
        off += bytes;
        return p;
    };

    float* Weff   = (float*)alloc((size_t)Ln * Hn * Dn * Dn * 4);
    float* beff   = (float*)alloc((size_t)Ln * Dn * 4);
    float* x1     = (float*)alloc((size_t)Bn * Pn * Dn * 4);
    float* x2     = (float*)alloc((size_t)Bn * Pn * Dn * 4);
    float* pooled = (float*)alloc((size_t)Bn * Dn * 4);

    // per-b bytes: Q,K,Vt bf16 (H*P*64 each) + AO fp32 (H*P*49)
    const size_t per_b = 3 * ((size_t)Hn * Pn * 64 * 2) + (size_t)Hn * Pn * Dn * 4;
    size_t fixed = (off + 255) & ~(size_t)255;
    int Bc = Bn;
    while (Bc > 1 && fixed + (size_t)Bc * per_b + 1024 > ws_size) Bc >>= 1;

    unsigned short* Qb  = (unsigned short*)alloc((size_t)Bc * Hn * Pn * 64 * 2);
    unsigned short* Kb  = (unsigned short*)alloc((size_t)Bc * Hn * Pn * 64 * 2);
    unsigned short* Vtb = (unsigned short*)alloc((size_t)Bc * Hn * Pn * 64 * 2);
    float*          AOb = (float*)alloc((size_t)Bc * Hn * Pn * Dn * 4);

    {
        int total = Ln * Hn * Dn * Dn + Ln * Dn;
        int g = (total + 255) / 256;
        prep_weff_kernel<<<g, 256, 0, stream>>>(Wh, bh, Wout, Weff, beff);
    }

    float* xs[2] = {x1, x2};
    for (int l = 0; l < Ln; ++l) {
        const float* xin = (l == 0) ? emb : xs[(l + 1) & 1];
        float* xout = xs[l & 1];
        const float* Wq_l = Wq + (size_t)l * Hn * Dn * Dn;
        const float* Wk_l = Wk + (size_t)l * Hn * Dn * Dn;
        const float* Wv_l = Wv + (size_t)l * Hn * Dn * Dn;
        const float* bq_l = bq + (size_t)l * Hn * Dn;
        const float* bk_l = bk + (size_t)l * Hn * Dn;
        const float* bv_l = bv + (size_t)l * Hn * Dn;
        const float* We_l = Weff + (size_t)l * Hn * Dn * Dn;
        const float* be_l = beff + (size_t)l * Dn;

        for (int b0 = 0; b0 < Bn; b0 += Bc) {
            dim3 g1(Bc * Pn / 256, Hn, 3);
            qkv_kernel<<<g1, 256, 0, stream>>>(xin, Wq_l, bq_l, Wk_l, bk_l, Wv_l, bv_l,
                                               Qb, Kb, Vtb, b0);
            dim3 g2(Pn / 64, Hn, Bc);
            attn_mfma_kernel<<<g2, 256, 0, stream>>>(Qb, Kb, Vtb, AOb);
            dim3 g3(Bc * Pn / 256);
            outproj_kernel<<<g3, 256, 0, stream>>>(AOb, We_l, be_l, xout, b0);
        }
    }

    pool_kernel<<<Bn, 64, 0, stream>>>(xs[1], pooled);
    head_kernel<<<1, 64, 0, stream>>>(pooled, labels, W1, b1, W2, b2, out);
}

// Round 3
// 1826.417 us; speedup vs baseline: 3.8346x; 1.3018x over previous
//
#include <hip/hip_runtime.h>
#include <hip/hip_bf16.h>
#include <math.h>

#define Bn 64
#define Pn 512
#define Hn 8
#define Ln 6

typedef __bf16 bf16x8 __attribute__((ext_vector_type(8)));
typedef float f32x4 __attribute__((ext_vector_type(4)));

static __device__ __forceinline__ unsigned short f2bf(float f) {
    return __builtin_bit_cast(unsigned short, __float2bfloat16(f));
}
static __device__ __forceinline__ float bf2f(unsigned short v) {
    unsigned int u = ((unsigned int)v) << 16;
    return __builtin_bit_cast(float, u);
}

// ---------- prep: cast/pad Wq,Wk,Wv -> [L][3][H][64 o][64 i] bf16 (zero-padded)
__global__ __launch_bounds__(256)
void prep_wqkv_kernel(const float* __restrict__ Wq, const float* __restrict__ Wk,
                      const float* __restrict__ Wv, unsigned short* __restrict__ out) {
    int idx = blockIdx.x * 256 + threadIdx.x;
    if (idx >= Ln * 3 * Hn * 4096) return;
    int i = idx & 63, o = (idx >> 6) & 63, h = (idx >> 12) & 7, t = idx >> 15;
    int mat = t % 3, l = t / 3;
    float v = 0.f;
    if (o < 49 && i < 49) {
        const float* src = (mat == 0) ? Wq : (mat == 1) ? Wk : Wv;
        v = src[(((size_t)(l * Hn + h) * 49) + o) * 49 + i];
    }
    out[idx] = f2bf(v);
}

// ---------- prep: Weff[l][h][o2 64][o 64] bf16 = sum_dd Wh[l,h,dd,o]*Wout[l,o2,h*49+dd]
//            beff[l][49] fp32
__global__ __launch_bounds__(256)
void prep_weff_kernel(const float* __restrict__ Wh, const float* __restrict__ bh,
                      const float* __restrict__ Wout,
                      unsigned short* __restrict__ Weff, float* __restrict__ beff) {
    const int NW = Ln * Hn * 4096;
    int idx = blockIdx.x * 256 + threadIdx.x;
    if (idx < NW) {
        int o = idx & 63, o2 = (idx >> 6) & 63, h = (idx >> 12) & 7, l = idx >> 15;
        float s = 0.f;
        if (o < 49 && o2 < 49) {
            const float* wh = Wh + ((size_t)(l * Hn + h) * 49) * 49 + o;   // [dd] stride 49
            const float* wo = Wout + ((size_t)l * 49 + o2) * 392 + h * 49; // [dd]
            for (int dd = 0; dd < 49; ++dd) s = fmaf(wh[dd * 49], wo[dd], s);
        }
        Weff[idx] = f2bf(s);
    } else if (idx < NW + Ln * 49) {
        int j = idx - NW;
        int l = j / 49, o2 = j % 49;
        const float* wo = Wout + ((size_t)l * 49 + o2) * 392;
        const float* bhl = bh + (size_t)l * 392;
        float s = 0.f;
        for (int cc = 0; cc < 392; ++cc) s = fmaf(bhl[cc], wo[cc], s);
        beff[j] = s;
    }
}

// ---------- prep: cast embedding -> x_bf [32768][64] padded
__global__ __launch_bounds__(256)
void cast_x_kernel(const float* __restrict__ emb, unsigned short* __restrict__ xbf) {
    int idx = blockIdx.x * 256 + threadIdx.x;   // 32768*64
    int row = idx >> 6, col = idx & 63;
    float v = (col < 49) ? emb[(size_t)row * 49 + col] : 0.f;
    xbf[idx] = f2bf(v);
}

// ---------- QKV via MFMA: block = 64 rows, loop 24 (mat,h) panels
__global__ __launch_bounds__(256)
void qkv_mfma_kernel(const unsigned short* __restrict__ xbf,
                     const unsigned short* __restrict__ Wqkv,   // layer base [3][8][64][64]
                     const float* __restrict__ bq_l, const float* __restrict__ bk_l,
                     const float* __restrict__ bv_l,
                     unsigned short* __restrict__ Qb, unsigned short* __restrict__ Kb,
                     unsigned short* __restrict__ Vt,
                     int b_off, int Bc) {
    __shared__ uint4 xlb4[512];
    __shared__ uint4 wlb4[512];
    __shared__ __align__(16) unsigned short stg[64 * 68];
    __shared__ float blds[1536];
    char* xlb = (char*)xlb4;
    char* wlb = (char*)wlb4;
    const int tid = threadIdx.x;
    const int w = tid >> 6, lane = tid & 63, g = lane >> 4, c = lane & 15;
    const int flat = blockIdx.x;
    const int bl = flat % Bc;            // chunk-local batch (XCD-local per b)
    const int tile = flat / Bc;          // 0..7
    const int r0 = bl * Pn + tile * 64;  // chunk-local flat row

    for (int t = tid; t < 1536; t += 256) {
        int mat = t >> 9, rem = t & 511, h = rem >> 6, o = rem & 63;
        const float* bb = (mat == 0) ? bq_l : (mat == 1) ? bk_l : bv_l;
        blds[t] = (o < 49) ? bb[h * 49 + o] : 0.f;
    }
    {
        const unsigned short* xg = xbf + ((size_t)b_off * Pn + r0) * 64;
        #pragma unroll
        for (int i = 0; i < 2; ++i) {
            int chunk = tid + i * 256;
            int row = chunk >> 3, c8 = chunk & 7;
            *(uint4*)(xlb + row * 128 + 16 * (c8 ^ (row & 7))) =
                *(const uint4*)(xg + row * 64 + c8 * 8);
        }
    }
    __syncthreads();

    const int rowa = w * 16 + c;
    bf16x8 a0 = *(const bf16x8*)(xlb + rowa * 128 + 16 * ((g    ) ^ (c & 7)));
    bf16x8 a1 = *(const bf16x8*)(xlb + rowa * 128 + 16 * ((g + 4) ^ (c & 7)));

    for (int panel = 0; panel < 24; ++panel) {
        const int mat = panel >> 3, h = panel & 7;
        const unsigned short* wg = Wqkv + (size_t)panel * 4096;
        #pragma unroll
        for (int i = 0; i < 2; ++i) {
            int chunk = tid + i * 256;
            int row = chunk >> 3, c8 = chunk & 7;
            *(uint4*)(wlb + row * 128 + 16 * (c8 ^ (row & 7))) =
                *(const uint4*)(wg + row * 64 + c8 * 8);
        }
        __syncthreads();

        f32x4 acc[4];
        #pragma unroll
        for (int bt = 0; bt < 4; ++bt) acc[bt] = (f32x4){0.f, 0.f, 0.f, 0.f};
        #pragma unroll
        for (int bt = 0; bt < 4; ++bt) {
            int rowb = bt * 16 + c;
            bf16x8 w0 = *(const bf16x8*)(wlb + rowb * 128 + 16 * ((g    ) ^ (rowb & 7)));
            bf16x8 w1 = *(const bf16x8*)(wlb + rowb * 128 + 16 * ((g + 4) ^ (rowb & 7)));
            acc[bt] = __builtin_amdgcn_mfma_f32_16x16x32_bf16(a0, w0, acc[bt], 0, 0, 0);
            acc[bt] = __builtin_amdgcn_mfma_f32_16x16x32_bf16(a1, w1, acc[bt], 0, 0, 0);
        }

        const float* bb = blds + mat * 512 + h * 64;
        if (mat < 2) {
            #pragma unroll
            for (int bt = 0; bt < 4; ++bt)
                #pragma unroll
                for (int r = 0; r < 4; ++r)
                    stg[(w * 16 + 4 * g + r) * 68 + bt * 16 + c] =
                        f2bf(acc[bt][r] + bb[bt * 16 + c]);
        } else {
            #pragma unroll
            for (int bt = 0; bt < 4; ++bt)
                #pragma unroll
                for (int r = 0; r < 4; ++r)
                    stg[(bt * 16 + c) * 68 + (w * 16 + 4 * g + r)] =
                        f2bf(acc[bt][r] + bb[bt * 16 + c]);
        }
        __syncthreads();

        if (mat < 2) {
            unsigned short* outp = (mat == 0) ? Qb : Kb;
            #pragma unroll
            for (int i = 0; i < 4; ++i) {
                int chunk = tid + i * 256;
                int prow = chunk >> 4, c4 = chunk & 15;
                uint2 v = *(const uint2*)((const char*)stg + prow * 136 + c4 * 8);
                int rr = r0 + prow;
                int bl2 = rr >> 9, p = rr & 511;
                *(uint2*)(outp + (((size_t)bl2 * Hn + h) * Pn + p) * 64 + c4 * 4) = v;
            }
        } else {
            const int bl2 = r0 >> 9, p0 = r0 & 511;
            #pragma unroll
            for (int i = 0; i < 4; ++i) {
                int chunk = tid + i * 256;
                int drow = chunk >> 4, c4 = chunk & 15;
                uint2 v = *(const uint2*)((const char*)stg + drow * 136 + c4 * 8);
                *(uint2*)(Vt + (((size_t)bl2 * Hn + h) * 64 + drow) * Pn + p0 + c4 * 4) = v;
            }
        }
    }
}

// ---------- fused attention + head-proj + out-proj: block = 2 waves x 32 q-rows
__global__ __launch_bounds__(128)
void attn_fused_kernel(const unsigned short* __restrict__ Qb,
                       const unsigned short* __restrict__ Kb,
                       const unsigned short* __restrict__ Vt,
                       const unsigned short* __restrict__ Weffl,  // [8][64][64] layer base
                       const float* __restrict__ beffl,           // [49]
                       unsigned short* __restrict__ xout,         // full [B*512][64]
                       int b_off, int Bc) {
    __shared__ uint4 Klb4[512], Vlb4[512], Wlb4[512], Plb4[512];
    __shared__ float bldc[64];
    char* Klb = (char*)Klb4;
    char* Vlb = (char*)Vlb4;
    char* Wlb = (char*)Wlb4;
    const int tid = threadIdx.x;
    const int w = tid >> 6, lane = tid & 63, g = lane >> 4, c = lane & 15;
    const int flat = blockIdx.x;
    const int bl = flat % Bc;   // same b -> same XCD (Bc multiple of 8)
    const int qt = flat / Bc;   // 0..7
    const int q0 = qt * 64;
    char* Plw = (char*)Plb4 + w * 4096;

    if (tid < 64) bldc[tid] = (tid < 49) ? beffl[tid] : 0.f;

    const float c1 = 1.4426950408889634f / 7.000001f;  // log2(e)/SCALE
    const float c2 = 43.2808512f;                      // 30*log2(e)

    f32x4 xacc[2][4];
    #pragma unroll
    for (int qs = 0; qs < 2; ++qs)
        #pragma unroll
        for (int bt = 0; bt < 4; ++bt) xacc[qs][bt] = (f32x4){0.f, 0.f, 0.f, 0.f};

    for (int h = 0; h < Hn; ++h) {
        const size_t bh = (size_t)bl * Hn + h;
        const unsigned short* wg = Weffl + (size_t)h * 4096;
        #pragma unroll
        for (int i = 0; i < 4; ++i) {
            int chunk = tid + i * 128;
            int row = chunk >> 3, c8 = chunk & 7;
            *(uint4*)(Wlb + row * 128 + 16 * (c8 ^ (row & 7))) =
                *(const uint4*)(wg + row * 64 + c8 * 8);
        }
        bf16x8 qf[2][2];
        #pragma unroll
        for (int qs = 0; qs < 2; ++qs) {
            const unsigned short* qp = Qb + (bh * Pn + q0 + w * 32 + qs * 16 + c) * 64;
            qf[qs][0] = *(const bf16x8*)(qp + g * 8);
            qf[qs][1] = *(const bf16x8*)(qp + g * 8 + 32);
        }
        float lsum[2][4];
        f32x4 oacc[2][4];
        #pragma unroll
        for (int qs = 0; qs < 2; ++qs)
            #pragma unroll
            for (int dt = 0; dt < 4; ++dt) {
                oacc[qs][dt] = (f32x4){0.f, 0.f, 0.f, 0.f};
                lsum[qs][dt] = 0.f;
            }

        const unsigned short* Kg0 = Kb + bh * (size_t)(Pn * 64);
        const unsigned short* Vg0 = Vt + bh * (size_t)(64 * Pn);
        for (int kt = 0; kt < 8; ++kt) {
            const unsigned short* Kg = Kg0 + kt * (64 * 64);
            const unsigned short* Vg = Vg0 + kt * 64;
            #pragma unroll
            for (int i = 0; i < 4; ++i) {
                int chunk = tid + i * 128;
                int row = chunk >> 3, c8 = chunk & 7;
                *(uint4*)(Klb + row * 128 + 16 * (c8 ^ (row & 7))) =
                    *(const uint4*)(Kg + row * 64 + c8 * 8);
                *(uint4*)(Vlb + row * 128 + 16 * (c8 ^ (row & 7))) =
                    *(const uint4*)(Vg + (size_t)row * Pn + c8 * 8);
            }
            __syncthreads();

            #pragma unroll
            for (int t = 0; t < 4; ++t) {
                const int krow = t * 16 + c;
                bf16x8 kf0 = *(const bf16x8*)(Klb + krow * 128 + 16 * ((g    ) ^ (krow & 7)));
                bf16x8 kf1 = *(const bf16x8*)(Klb + krow * 128 + 16 * ((g + 4) ^ (krow & 7)));
                #pragma unroll
                for (int qs = 0; qs < 2; ++qs) {
                    f32x4 s4 = {0.f, 0.f, 0.f, 0.f};
                    s4 = __builtin_amdgcn_mfma_f32_16x16x32_bf16(qf[qs][0], kf0, s4, 0, 0, 0);
                    s4 = __builtin_amdgcn_mfma_f32_16x16x32_bf16(qf[qs][1], kf1, s4, 0, 0, 0);
                    #pragma unroll
                    for (int r = 0; r < 4; ++r) {
                        float u = fminf(fmaxf(s4[r] * c1, -c2), c2);
                        float p = exp2f(u - c2);      // fixed-max softmax (post-clip max=30)
                        lsum[qs][r] += p;
                        int prow = qs * 16 + 4 * g + r;
                        *(unsigned short*)(Plw + prow * 128 + ((2 * krow) ^ ((prow & 7) << 4))) = f2bf(p);
                    }
                }
            }
            asm volatile("s_waitcnt lgkmcnt(0)" ::: "memory");
            __builtin_amdgcn_sched_barrier(0);

            #pragma unroll
            for (int kk = 0; kk < 2; ++kk) {
                bf16x8 pa0 = *(const bf16x8*)(Plw + (c     ) * 128 + 16 * ((g + 4 * kk) ^ (c & 7)));
                bf16x8 pa1 = *(const bf16x8*)(Plw + (16 + c) * 128 + 16 * ((g + 4 * kk) ^ (c & 7)));
                #pragma unroll
                for (int dt = 0; dt < 4; ++dt) {
                    const int vrow = dt * 16 + c;
                    bf16x8 vf = *(const bf16x8*)(Vlb + vrow * 128 + 16 * ((g + 4 * kk) ^ (vrow & 7)));
                    oacc[0][dt] = __builtin_amdgcn_mfma_f32_16x16x32_bf16(pa0, vf, oacc[0][dt], 0, 0, 0);
                    oacc[1][dt] = __builtin_amdgcn_mfma_f32_16x16x32_bf16(pa1, vf, oacc[1][dt], 0, 0, 0);
                }
            }
            __syncthreads();
        }

        // normalize, write PA tile (bf16) into Plw
        float rinv[2][4];
        #pragma unroll
        for (int qs = 0; qs < 2; ++qs)
            #pragma unroll
            for (int r = 0; r < 4; ++r) {
                float v = lsum[qs][r];
                v += __shfl_xor(v, 1);
                v += __shfl_xor(v, 2);
                v += __shfl_xor(v, 4);
                v += __shfl_xor(v, 8);
                rinv[qs][r] = 1.0f / v;
            }
        #pragma unroll
        for (int qs = 0; qs < 2; ++qs)
            #pragma unroll
            for (int dt = 0; dt < 4; ++dt)
                #pragma unroll
                for (int r = 0; r < 4; ++r) {
                    int prow = qs * 16 + 4 * g + r;
                    int col = dt * 16 + c;
                    *(unsigned short*)(Plw + prow * 128 + ((2 * col) ^ ((prow & 7) << 4))) =
                        f2bf(oacc[qs][dt][r] * rinv[qs][r]);
                }
        asm volatile("s_waitcnt lgkmcnt(0)" ::: "memory");
        __builtin_amdgcn_sched_barrier(0);

        bf16x8 pa2[2][2];
        #pragma unroll
        for (int qs = 0; qs < 2; ++qs)
            #pragma unroll
            for (int kh = 0; kh < 2; ++kh)
                pa2[qs][kh] = *(const bf16x8*)(Plw + (qs * 16 + c) * 128 + 16 * ((g + 4 * kh) ^ (c & 7)));
        #pragma unroll
        for (int bt = 0; bt < 4; ++bt) {
            int rowb = bt * 16 + c;
            bf16x8 wf0 = *(const bf16x8*)(Wlb + rowb * 128 + 16 * ((g    ) ^ (rowb & 7)));
            bf16x8 wf1 = *(const bf16x8*)(Wlb + rowb * 128 + 16 * ((g + 4) ^ (rowb & 7)));
            xacc[0][bt] = __builtin_amdgcn_mfma_f32_16x16x32_bf16(pa2[0][0], wf0, xacc[0][bt], 0, 0, 0);
            xacc[0][bt] = __builtin_amdgcn_mfma_f32_16x16x32_bf16(pa2[0][1], wf1, xacc[0][bt], 0, 0, 0);
            xacc[1][bt] = __builtin_amdgcn_mfma_f32_16x16x32_bf16(pa2[1][0], wf0, xacc[1][bt], 0, 0, 0);
            xacc[1][bt] = __builtin_amdgcn_mfma_f32_16x16x32_bf16(pa2[1][1], wf1, xacc[1][bt], 0, 0, 0);
        }
        __syncthreads();   // protect Wlb/Plw/Klb/Vlb before next h
    }

    // epilogue: + beff, bf16, coalesced store via Plw
    #pragma unroll
    for (int qs = 0; qs < 2; ++qs)
        #pragma unroll
        for (int bt = 0; bt < 4; ++bt)
            #pragma unroll
            for (int r = 0; r < 4; ++r) {
                int prow = qs * 16 + 4 * g + r;
                int col = bt * 16 + c;
                *(unsigned short*)(Plw + prow * 128 + ((2 * col) ^ ((prow & 7) << 4))) =
                    f2bf(xacc[qs][bt][r] + bldc[col]);
            }
    asm volatile("s_waitcnt lgkmcnt(0)" ::: "memory");
    __builtin_amdgcn_sched_barrier(0);
    #pragma unroll
    for (int i = 0; i < 4; ++i) {
        int chunk = i * 64 + lane;
        int row = chunk >> 3, c8 = chunk & 7;
        uint4 v = *(const uint4*)(Plw + row * 128 + 16 * (c8 ^ (row & 7)));
        size_t grow = (size_t)(b_off + bl) * Pn + q0 + w * 32 + row;
        *(uint4*)(xout + grow * 64 + c8 * 8) = v;
    }
}

// ---------- mean-pool over P (bf16 input)
__global__ __launch_bounds__(256)
void pool_kernel(const unsigned short* __restrict__ x, float* __restrict__ pooled) {
    __shared__ float red[256];
    const int b = blockIdx.x;
    const int tid = threadIdx.x;
    const int ps = tid >> 6, d = tid & 63;
    float s = 0.f;
    for (int p = ps; p < Pn; p += 4) s += bf2f(x[((size_t)b * Pn + p) * 64 + d]);
    red[tid] = s;
    __syncthreads();
    if (tid < 64) {
        float t = red[tid] + red[tid + 64] + red[tid + 128] + red[tid + 192];
        if (tid < 49) pooled[b * 49 + tid] = t * (1.0f / Pn);
    }
}

// ---------- MLP + log-softmax + NLL
__global__ __launch_bounds__(64)
void head_kernel(const float* __restrict__ pooled, const int* __restrict__ labels,
                 const float* __restrict__ W1, const float* __restrict__ b1,
                 const float* __restrict__ W2, const float* __restrict__ b2,
                 float* __restrict__ out) {
    __shared__ float lloss[64];
    const int b = threadIdx.x;
    float pr[49];
    #pragma unroll
    for (int i = 0; i < 49; ++i) pr[i] = pooled[b * 49 + i];
    float hh[25];
    for (int j = 0; j < 25; ++j) {
        float s = b1[j];
        for (int i = 0; i < 49; ++i) s = fmaf(pr[i], W1[j * 49 + i], s);
        hh[j] = fmaxf(s, 0.f);
    }
    float lg[10];
    float m = -1e30f;
    for (int k = 0; k < 10; ++k) {
        float s = b2[k];
        for (int j = 0; j < 25; ++j) s = fmaf(hh[j], W2[k * 25 + j], s);
        lg[k] = s;
        m = fmaxf(m, s);
    }
    float se = 0.f;
    for (int k = 0; k < 10; ++k) se += __expf(lg[k] - m);
    float lse = m + __logf(se);
    int lbl = labels[b];
    lloss[b] = lse - lg[lbl];
    __syncthreads();
    if (b == 0) {
        float s = 0.f;
        for (int i = 0; i < 64; ++i) s += lloss[i];
        out[0] = s * (1.0f / 64.0f);
    }
}

extern "C" void kernel_launch(void* const* d_in, const int* in_sizes, int n_in,
                              void* d_out, int out_size, void* d_ws, size_t ws_size,
                              hipStream_t stream) {
    const float* emb    = (const float*)d_in[0];
    const int*   labels = (const int*)d_in[1];
    const float* Wq = (const float*)d_in[2];
    const float* bq = (const float*)d_in[3];
    const float* Wk = (const float*)d_in[4];
    const float* bk = (const float*)d_in[5];
    const float* Wv = (const float*)d_in[6];
    const float* bv = (const float*)d_in[7];
    const float* Wh = (const float*)d_in[8];
    const float* bhp = (const float*)d_in[9];
    const float* Wout = (const float*)d_in[10];
    const float* W1 = (const float*)d_in[11];
    const float* b1 = (const float*)d_in[12];
    const float* W2 = (const float*)d_in[13];
    const float* b2 = (const float*)d_in[14];
    float* out = (float*)d_out;

    char* base = (char*)d_ws;
    size_t off = 0;
    auto alloc = [&](size_t bytes) {
        off = (off + 255) & ~(size_t)255;
        char* p = base + off;
        off += bytes;
        return p;
    };

    unsigned short* WqkvB = (unsigned short*)alloc((size_t)Ln * 3 * Hn * 4096 * 2);
    unsigned short* WeffB = (unsigned short*)alloc((size_t)Ln * Hn * 4096 * 2);
    float*          beffB = (float*)alloc((size_t)Ln * 49 * 4);
    unsigned short* xA    = (unsigned short*)alloc((size_t)Bn * Pn * 64 * 2);
    unsigned short* xB    = (unsigned short*)alloc((size_t)Bn * Pn * 64 * 2);
    float*          pooled = (float*)alloc((size_t)Bn * 49 * 4);

    const size_t per_b = 3 * ((size_t)Hn * Pn * 64 * 2);   // Q + K + Vt bf16
    size_t fixed = (off + 255) & ~(size_t)255;
    int Bc = Bn;
    while (Bc > 8 && fixed + (size_t)Bc * per_b + 4096 > ws_size) Bc >>= 1;

    unsigned short* Qb  = (unsigned short*)alloc((size_t)Bc * Hn * Pn * 64 * 2);
    unsigned short* Kb  = (unsigned short*)alloc((size_t)Bc * Hn * Pn * 64 * 2);
    unsigned short* Vtb = (unsigned short*)alloc((size_t)Bc * Hn * Pn * 64 * 2);

    prep_wqkv_kernel<<<(Ln * 3 * Hn * 4096 + 255) / 256, 256, 0, stream>>>(Wq, Wk, Wv, WqkvB);
    prep_weff_kernel<<<(Ln * Hn * 4096 + Ln * 49 + 255) / 256, 256, 0, stream>>>(Wh, bhp, Wout, WeffB, beffB);
    cast_x_kernel<<<(Bn * Pn * 64) / 256, 256, 0, stream>>>(emb, xA);

    unsigned short* cur = xA;
    unsigned short* nxt = xB;
    for (int l = 0; l < Ln; ++l) {
        const unsigned short* Wqkv_l = WqkvB + (size_t)l * 3 * Hn * 4096;
        const unsigned short* Weff_l = WeffB + (size_t)l * Hn * 4096;
        const float* beff_l = beffB + (size_t)l * 49;
        const float* bq_l = bq + (size_t)l * Hn * 49;
        const float* bk_l = bk + (size_t)l * Hn * 49;
        const float* bv_l = bv + (size_t)l * Hn * 49;

        for (int b0 = 0; b0 < Bn; b0 += Bc) {
            qkv_mfma_kernel<<<Bc * 8, 256, 0, stream>>>(cur, Wqkv_l, bq_l, bk_l, bv_l,
                                                        Qb, Kb, Vtb, b0, Bc);
            attn_fused_kernel<<<8 * Bc, 128, 0, stream>>>(Qb, Kb, Vtb, Weff_l, beff_l,
                                                          nxt, b0, Bc);
        }
        unsigned short* tmp = cur; cur = nxt; nxt = tmp;
    }

    pool_kernel<<<Bn, 256, 0, stream>>>(cur, pooled);
    head_kernel<<<1, 64, 0, stream>>>(pooled, labels, W1, b1, W2, b2, out);
}

// Round 4
// 1120.511 us; speedup vs baseline: 6.2504x; 1.6300x over previous
//
#include <hip/hip_runtime.h>
#include <hip/hip_bf16.h>
#include <math.h>

#define Bn 64
#define Pn 512
#define Hn 8
#define Ln 6

typedef __bf16 bf16x8 __attribute__((ext_vector_type(8)));
typedef float f32x4 __attribute__((ext_vector_type(4)));

static __device__ __forceinline__ unsigned short f2bf(float f) {
    return __builtin_bit_cast(unsigned short, __float2bfloat16(f));
}
static __device__ __forceinline__ float bf2f(unsigned short v) {
    unsigned int u = ((unsigned int)v) << 16;
    return __builtin_bit_cast(float, u);
}

// ---------- prep: cast/pad Wq,Wk,Wv -> [L][3][H][64 o][64 i] bf16 (zero-padded)
__global__ __launch_bounds__(256)
void prep_wqkv_kernel(const float* __restrict__ Wq, const float* __restrict__ Wk,
                      const float* __restrict__ Wv, unsigned short* __restrict__ out) {
    int idx = blockIdx.x * 256 + threadIdx.x;
    if (idx >= Ln * 3 * Hn * 4096) return;
    int i = idx & 63, o = (idx >> 6) & 63, h = (idx >> 12) & 7, t = idx >> 15;
    int mat = t % 3, l = t / 3;
    float v = 0.f;
    if (o < 49 && i < 49) {
        const float* src = (mat == 0) ? Wq : (mat == 1) ? Wk : Wv;
        v = src[(((size_t)(l * Hn + h) * 49) + o) * 49 + i];
    }
    out[idx] = f2bf(v);
}

// ---------- prep: Weff[l][h][o2 64][o 64] bf16 = sum_dd Wh[l,h,dd,o]*Wout[l,o2,h*49+dd]
__global__ __launch_bounds__(256)
void prep_weff_kernel(const float* __restrict__ Wh, const float* __restrict__ bh,
                      const float* __restrict__ Wout,
                      unsigned short* __restrict__ Weff, float* __restrict__ beff) {
    const int NW = Ln * Hn * 4096;
    int idx = blockIdx.x * 256 + threadIdx.x;
    if (idx < NW) {
        int o = idx & 63, o2 = (idx >> 6) & 63, h = (idx >> 12) & 7, l = idx >> 15;
        float s = 0.f;
        if (o < 49 && o2 < 49) {
            const float* wh = Wh + ((size_t)(l * Hn + h) * 49) * 49 + o;   // [dd] stride 49
            const float* wo = Wout + ((size_t)l * 49 + o2) * 392 + h * 49; // [dd]
            for (int dd = 0; dd < 49; ++dd) s = fmaf(wh[dd * 49], wo[dd], s);
        }
        Weff[idx] = f2bf(s);
    } else if (idx < NW + Ln * 49) {
        int j = idx - NW;
        int l = j / 49, o2 = j % 49;
        const float* wo = Wout + ((size_t)l * 49 + o2) * 392;
        const float* bhl = bh + (size_t)l * 392;
        float s = 0.f;
        for (int cc = 0; cc < 392; ++cc) s = fmaf(bhl[cc], wo[cc], s);
        beff[j] = s;
    }
}

// ---------- prep: cast embedding -> x_bf [32768][64] padded
__global__ __launch_bounds__(256)
void cast_x_kernel(const float* __restrict__ emb, unsigned short* __restrict__ xbf) {
    int idx = blockIdx.x * 256 + threadIdx.x;
    int row = idx >> 6, col = idx & 63;
    float v = (col < 49) ? emb[(size_t)row * 49 + col] : 0.f;
    xbf[idx] = f2bf(v);
}

// ---------- QKV via MFMA: block = 64 rows, loop 24 (mat,h) panels
__global__ __launch_bounds__(256)
void qkv_mfma_kernel(const unsigned short* __restrict__ xbf,
                     const unsigned short* __restrict__ Wqkv,
                     const float* __restrict__ bq_l, const float* __restrict__ bk_l,
                     const float* __restrict__ bv_l,
                     unsigned short* __restrict__ Qb, unsigned short* __restrict__ Kb,
                     unsigned short* __restrict__ Vt,
                     int b_off, int Bc) {
    __shared__ uint4 xlb4[512];
    __shared__ uint4 wlb4[512];
    __shared__ __align__(16) unsigned short stg[64 * 68];
    __shared__ float blds[1536];
    char* xlb = (char*)xlb4;
    char* wlb = (char*)wlb4;
    const int tid = threadIdx.x;
    const int w = tid >> 6, lane = tid & 63, g = lane >> 4, c = lane & 15;
    const int flat = blockIdx.x;
    const int bl = flat % Bc;
    const int tile = flat / Bc;
    const int r0 = bl * Pn + tile * 64;

    for (int t = tid; t < 1536; t += 256) {
        int mat = t >> 9, rem = t & 511, h = rem >> 6, o = rem & 63;
        const float* bb = (mat == 0) ? bq_l : (mat == 1) ? bk_l : bv_l;
        blds[t] = (o < 49) ? bb[h * 49 + o] : 0.f;
    }
    {
        const unsigned short* xg = xbf + ((size_t)b_off * Pn + r0) * 64;
        #pragma unroll
        for (int i = 0; i < 2; ++i) {
            int chunk = tid + i * 256;
            int row = chunk >> 3, c8 = chunk & 7;
            *(uint4*)(xlb + row * 128 + 16 * (c8 ^ (row & 7))) =
                *(const uint4*)(xg + row * 64 + c8 * 8);
        }
    }
    __syncthreads();

    const int rowa = w * 16 + c;
    bf16x8 a0 = *(const bf16x8*)(xlb + rowa * 128 + 16 * ((g    ) ^ (c & 7)));
    bf16x8 a1 = *(const bf16x8*)(xlb + rowa * 128 + 16 * ((g + 4) ^ (c & 7)));

    for (int panel = 0; panel < 24; ++panel) {
        const int mat = panel >> 3, h = panel & 7;
        const unsigned short* wg = Wqkv + (size_t)panel * 4096;
        #pragma unroll
        for (int i = 0; i < 2; ++i) {
            int chunk = tid + i * 256;
            int row = chunk >> 3, c8 = chunk & 7;
            *(uint4*)(wlb + row * 128 + 16 * (c8 ^ (row & 7))) =
                *(const uint4*)(wg + row * 64 + c8 * 8);
        }
        __syncthreads();

        f32x4 acc[4];
        #pragma unroll
        for (int bt = 0; bt < 4; ++bt) acc[bt] = (f32x4){0.f, 0.f, 0.f, 0.f};
        #pragma unroll
        for (int bt = 0; bt < 4; ++bt) {
            int rowb = bt * 16 + c;
            bf16x8 w0 = *(const bf16x8*)(wlb + rowb * 128 + 16 * ((g    ) ^ (rowb & 7)));
            bf16x8 w1 = *(const bf16x8*)(wlb + rowb * 128 + 16 * ((g + 4) ^ (rowb & 7)));
            acc[bt] = __builtin_amdgcn_mfma_f32_16x16x32_bf16(a0, w0, acc[bt], 0, 0, 0);
            acc[bt] = __builtin_amdgcn_mfma_f32_16x16x32_bf16(a1, w1, acc[bt], 0, 0, 0);
        }

        const float* bb = blds + mat * 512 + h * 64;
        if (mat < 2) {
            #pragma unroll
            for (int bt = 0; bt < 4; ++bt)
                #pragma unroll
                for (int r = 0; r < 4; ++r)
                    stg[(w * 16 + 4 * g + r) * 68 + bt * 16 + c] =
                        f2bf(acc[bt][r] + bb[bt * 16 + c]);
        } else {
            #pragma unroll
            for (int bt = 0; bt < 4; ++bt)
                #pragma unroll
                for (int r = 0; r < 4; ++r)
                    stg[(bt * 16 + c) * 68 + (w * 16 + 4 * g + r)] =
                        f2bf(acc[bt][r] + bb[bt * 16 + c]);
        }
        __syncthreads();

        if (mat < 2) {
            unsigned short* outp = (mat == 0) ? Qb : Kb;
            #pragma unroll
            for (int i = 0; i < 4; ++i) {
                int chunk = tid + i * 256;
                int prow = chunk >> 4, c4 = chunk & 15;
                uint2 v = *(const uint2*)((const char*)stg + prow * 136 + c4 * 8);
                int rr = r0 + prow;
                int bl2 = rr >> 9, p = rr & 511;
                *(uint2*)(outp + (((size_t)bl2 * Hn + h) * Pn + p) * 64 + c4 * 4) = v;
            }
        } else {
            const int bl2 = r0 >> 9, p0 = r0 & 511;
            #pragma unroll
            for (int i = 0; i < 4; ++i) {
                int chunk = tid + i * 256;
                int drow = chunk >> 4, c4 = chunk & 15;
                uint2 v = *(const uint2*)((const char*)stg + drow * 136 + c4 * 8);
                *(uint2*)(Vt + (((size_t)bl2 * Hn + h) * 64 + drow) * Pn + p0 + c4 * 4) = v;
            }
        }
    }
}

// ---------- per-head attention: block = 2 waves x 64 q-rows of one (b,h); writes AO bf16
__global__ __launch_bounds__(128)
void attn_head_kernel(const unsigned short* __restrict__ Qb,
                      const unsigned short* __restrict__ Kb,
                      const unsigned short* __restrict__ Vt,
                      unsigned short* __restrict__ AO,   // [Bc][H][P][64] bf16
                      int Bc) {
    __shared__ uint4 Klb4[512], Vlb4[512], Plb4[512];
    char* Klb = (char*)Klb4;
    char* Vlb = (char*)Vlb4;
    const int tid = threadIdx.x;
    const int w = tid >> 6, lane = tid & 63, g = lane >> 4, c = lane & 15;
    // swizzled decode: flat = (u>>3)*64 + qt*8 + (u&7); u = bl*8+h
    const int flat = blockIdx.x;
    const int u = (flat >> 6) * 8 + (flat & 7);
    const int qt = (flat >> 3) & 7;
    const size_t bh = (size_t)u;
    const int q0 = qt * 64;
    char* Plw = (char*)Plb4 + w * 4096;

    const float c1 = 1.4426950408889634f / 7.000001f;  // log2(e)/SCALE
    const float c2 = 43.2808512f;                      // 30*log2(e)

    bf16x8 qf[2][2];
    #pragma unroll
    for (int qs = 0; qs < 2; ++qs) {
        const unsigned short* qp = Qb + (bh * Pn + q0 + w * 32 + qs * 16 + c) * 64;
        qf[qs][0] = *(const bf16x8*)(qp + g * 8);
        qf[qs][1] = *(const bf16x8*)(qp + g * 8 + 32);
    }
    float lsum[2][4];
    f32x4 oacc[2][4];
    #pragma unroll
    for (int qs = 0; qs < 2; ++qs)
        #pragma unroll
        for (int dt = 0; dt < 4; ++dt) {
            oacc[qs][dt] = (f32x4){0.f, 0.f, 0.f, 0.f};
            lsum[qs][dt] = 0.f;
        }

    const unsigned short* Kg0 = Kb + bh * (size_t)(Pn * 64);
    const unsigned short* Vg0 = Vt + bh * (size_t)(64 * Pn);
    for (int kt = 0; kt < 8; ++kt) {
        const unsigned short* Kg = Kg0 + kt * (64 * 64);
        const unsigned short* Vg = Vg0 + kt * 64;
        #pragma unroll
        for (int i = 0; i < 4; ++i) {
            int chunk = tid + i * 128;
            int row = chunk >> 3, c8 = chunk & 7;
            *(uint4*)(Klb + row * 128 + 16 * (c8 ^ (row & 7))) =
                *(const uint4*)(Kg + row * 64 + c8 * 8);
            *(uint4*)(Vlb + row * 128 + 16 * (c8 ^ (row & 7))) =
                *(const uint4*)(Vg + (size_t)row * Pn + c8 * 8);
        }
        __syncthreads();

        #pragma unroll
        for (int t = 0; t < 4; ++t) {
            const int krow = t * 16 + c;
            bf16x8 kf0 = *(const bf16x8*)(Klb + krow * 128 + 16 * ((g    ) ^ (krow & 7)));
            bf16x8 kf1 = *(const bf16x8*)(Klb + krow * 128 + 16 * ((g + 4) ^ (krow & 7)));
            #pragma unroll
            for (int qs = 0; qs < 2; ++qs) {
                f32x4 s4 = {0.f, 0.f, 0.f, 0.f};
                s4 = __builtin_amdgcn_mfma_f32_16x16x32_bf16(qf[qs][0], kf0, s4, 0, 0, 0);
                s4 = __builtin_amdgcn_mfma_f32_16x16x32_bf16(qf[qs][1], kf1, s4, 0, 0, 0);
                #pragma unroll
                for (int r = 0; r < 4; ++r) {
                    float uu = fminf(fmaxf(s4[r] * c1, -c2), c2);
                    float p = exp2f(uu - c2);      // fixed-max softmax (post-clip max=30)
                    lsum[qs][r] += p;
                    int prow = qs * 16 + 4 * g + r;
                    *(unsigned short*)(Plw + prow * 128 + ((2 * krow) ^ ((prow & 7) << 4))) = f2bf(p);
                }
            }
        }
        asm volatile("s_waitcnt lgkmcnt(0)" ::: "memory");
        __builtin_amdgcn_sched_barrier(0);

        #pragma unroll
        for (int kk = 0; kk < 2; ++kk) {
            bf16x8 pa0 = *(const bf16x8*)(Plw + (c     ) * 128 + 16 * ((g + 4 * kk) ^ (c & 7)));
            bf16x8 pa1 = *(const bf16x8*)(Plw + (16 + c) * 128 + 16 * ((g + 4 * kk) ^ (c & 7)));
            #pragma unroll
            for (int dt = 0; dt < 4; ++dt) {
                const int vrow = dt * 16 + c;
                bf16x8 vf = *(const bf16x8*)(Vlb + vrow * 128 + 16 * ((g + 4 * kk) ^ (vrow & 7)));
                oacc[0][dt] = __builtin_amdgcn_mfma_f32_16x16x32_bf16(pa0, vf, oacc[0][dt], 0, 0, 0);
                oacc[1][dt] = __builtin_amdgcn_mfma_f32_16x16x32_bf16(pa1, vf, oacc[1][dt], 0, 0, 0);
            }
        }
        __syncthreads();
    }

    // normalize and write AO (bf16) via swizzled LDS re-tile
    float rinv[2][4];
    #pragma unroll
    for (int qs = 0; qs < 2; ++qs)
        #pragma unroll
        for (int r = 0; r < 4; ++r) {
            float v = lsum[qs][r];
            v += __shfl_xor(v, 1);
            v += __shfl_xor(v, 2);
            v += __shfl_xor(v, 4);
            v += __shfl_xor(v, 8);
            rinv[qs][r] = 1.0f / v;
        }
    #pragma unroll
    for (int qs = 0; qs < 2; ++qs)
        #pragma unroll
        for (int dt = 0; dt < 4; ++dt)
            #pragma unroll
            for (int r = 0; r < 4; ++r) {
                int prow = qs * 16 + 4 * g + r;
                int col = dt * 16 + c;
                *(unsigned short*)(Plw + prow * 128 + ((2 * col) ^ ((prow & 7) << 4))) =
                    f2bf(oacc[qs][dt][r] * rinv[qs][r]);
            }
    asm volatile("s_waitcnt lgkmcnt(0)" ::: "memory");
    __builtin_amdgcn_sched_barrier(0);
    #pragma unroll
    for (int i = 0; i < 4; ++i) {
        int chunk = i * 64 + lane;
        int row = chunk >> 3, c8 = chunk & 7;
        uint4 v = *(const uint4*)(Plw + row * 128 + 16 * (c8 ^ (row & 7)));
        size_t grow = bh * Pn + q0 + w * 32 + row;
        *(uint4*)(AO + grow * 64 + c8 * 8) = v;
    }
}

// ---------- out-projection GEMM: x[row][o2] = sum_h AO[h-tile] x Weff[h] ; K = 8x64
__global__ __launch_bounds__(256)
void outproj_mfma_kernel(const unsigned short* __restrict__ AO,    // [Bc][H][P][64]
                         const unsigned short* __restrict__ Weffl, // [8][64][64]
                         const float* __restrict__ beffl,          // [49]
                         unsigned short* __restrict__ xout,        // full [B*512][64]
                         int b_off, int Bc) {
    __shared__ uint4 Alb4[512], Wlb4[512];
    __shared__ __align__(16) unsigned short stg[64 * 68];
    __shared__ float bldc[64];
    char* Alb = (char*)Alb4;
    char* Wlb = (char*)Wlb4;
    const int tid = threadIdx.x;
    const int w = tid >> 6, lane = tid & 63, g = lane >> 4, c = lane & 15;
    const int flat = blockIdx.x;
    const int bl = flat % Bc;
    const int tile = flat / Bc;
    const int p0 = tile * 64;

    if (tid < 64) bldc[tid] = (tid < 49) ? beffl[tid] : 0.f;

    f32x4 acc[4];
    #pragma unroll
    for (int bt = 0; bt < 4; ++bt) acc[bt] = (f32x4){0.f, 0.f, 0.f, 0.f};

    for (int h = 0; h < Hn; ++h) {
        const unsigned short* Ag = AO + (((size_t)bl * Hn + h) * Pn + p0) * 64;
        const unsigned short* Wg = Weffl + (size_t)h * 4096;
        #pragma unroll
        for (int i = 0; i < 2; ++i) {
            int chunk = tid + i * 256;
            int row = chunk >> 3, c8 = chunk & 7;
            *(uint4*)(Alb + row * 128 + 16 * (c8 ^ (row & 7))) =
                *(const uint4*)(Ag + row * 64 + c8 * 8);
            *(uint4*)(Wlb + row * 128 + 16 * (c8 ^ (row & 7))) =
                *(const uint4*)(Wg + row * 64 + c8 * 8);
        }
        __syncthreads();

        const int rowa = w * 16 + c;
        bf16x8 a0 = *(const bf16x8*)(Alb + rowa * 128 + 16 * ((g    ) ^ (c & 7)));
        bf16x8 a1 = *(const bf16x8*)(Alb + rowa * 128 + 16 * ((g + 4) ^ (c & 7)));
        #pragma unroll
        for (int bt = 0; bt < 4; ++bt) {
            int rowb = bt * 16 + c;
            bf16x8 w0 = *(const bf16x8*)(Wlb + rowb * 128 + 16 * ((g    ) ^ (rowb & 7)));
            bf16x8 w1 = *(const bf16x8*)(Wlb + rowb * 128 + 16 * ((g + 4) ^ (rowb & 7)));
            acc[bt] = __builtin_amdgcn_mfma_f32_16x16x32_bf16(a0, w0, acc[bt], 0, 0, 0);
            acc[bt] = __builtin_amdgcn_mfma_f32_16x16x32_bf16(a1, w1, acc[bt], 0, 0, 0);
        }
        __syncthreads();
    }

    #pragma unroll
    for (int bt = 0; bt < 4; ++bt)
        #pragma unroll
        for (int r = 0; r < 4; ++r)
            stg[(w * 16 + 4 * g + r) * 68 + bt * 16 + c] =
                f2bf(acc[bt][r] + bldc[bt * 16 + c]);
    __syncthreads();

    #pragma unroll
    for (int i = 0; i < 4; ++i) {
        int chunk = tid + i * 256;
        int prow = chunk >> 4, c4 = chunk & 15;
        uint2 v = *(const uint2*)((const char*)stg + prow * 136 + c4 * 8);
        size_t grow = (size_t)(b_off + bl) * Pn + p0 + prow;
        *(uint2*)(xout + grow * 64 + c4 * 4) = v;
    }
}

// ---------- mean-pool over P (bf16 input)
__global__ __launch_bounds__(256)
void pool_kernel(const unsigned short* __restrict__ x, float* __restrict__ pooled) {
    __shared__ float red[256];
    const int b = blockIdx.x;
    const int tid = threadIdx.x;
    const int ps = tid >> 6, d = tid & 63;
    float s = 0.f;
    for (int p = ps; p < Pn; p += 4) s += bf2f(x[((size_t)b * Pn + p) * 64 + d]);
    red[tid] = s;
    __syncthreads();
    if (tid < 64) {
        float t = red[tid] + red[tid + 64] + red[tid + 128] + red[tid + 192];
        if (tid < 49) pooled[b * 49 + tid] = t * (1.0f / Pn);
    }
}

// ---------- MLP + log-softmax + NLL
__global__ __launch_bounds__(64)
void head_kernel(const float* __restrict__ pooled, const int* __restrict__ labels,
                 const float* __restrict__ W1, const float* __restrict__ b1,
                 const float* __restrict__ W2, const float* __restrict__ b2,
                 float* __restrict__ out) {
    __shared__ float lloss[64];
    const int b = threadIdx.x;
    float pr[49];
    #pragma unroll
    for (int i = 0; i < 49; ++i) pr[i] = pooled[b * 49 + i];
    float hh[25];
    for (int j = 0; j < 25; ++j) {
        float s = b1[j];
        for (int i = 0; i < 49; ++i) s = fmaf(pr[i], W1[j * 49 + i], s);
        hh[j] = fmaxf(s, 0.f);
    }
    float lg[10];
    float m = -1e30f;
    for (int k = 0; k < 10; ++k) {
        float s = b2[k];
        for (int j = 0; j < 25; ++j) s = fmaf(hh[j], W2[k * 25 + j], s);
        lg[k] = s;
        m = fmaxf(m, s);
    }
    float se = 0.f;
    for (int k = 0; k < 10; ++k) se += __expf(lg[k] - m);
    float lse = m + __logf(se);
    int lbl = labels[b];
    lloss[b] = lse - lg[lbl];
    __syncthreads();
    if (b == 0) {
        float s = 0.f;
        for (int i = 0; i < 64; ++i) s += lloss[i];
        out[0] = s * (1.0f / 64.0f);
    }
}

extern "C" void kernel_launch(void* const* d_in, const int* in_sizes, int n_in,
                              void* d_out, int out_size, void* d_ws, size_t ws_size,
                              hipStream_t stream) {
    const float* emb    = (const float*)d_in[0];
    const int*   labels = (const int*)d_in[1];
    const float* Wq = (const float*)d_in[2];
    const float* bq = (const float*)d_in[3];
    const float* Wk = (const float*)d_in[4];
    const float* bk = (const float*)d_in[5];
    const float* Wv = (const float*)d_in[6];
    const float* bv = (const float*)d_in[7];
    const float* Wh = (const float*)d_in[8];
    const float* bhp = (const float*)d_in[9];
    const float* Wout = (const float*)d_in[10];
    const float* W1 = (const float*)d_in[11];
    const float* b1 = (const float*)d_in[12];
    const float* W2 = (const float*)d_in[13];
    const float* b2 = (const float*)d_in[14];
    float* out = (float*)d_out;

    char* base = (char*)d_ws;
    size_t off = 0;
    auto alloc = [&](size_t bytes) {
        off = (off + 255) & ~(size_t)255;
        char* p = base + off;
        off += bytes;
        return p;
    };

    unsigned short* WqkvB = (unsigned short*)alloc((size_t)Ln * 3 * Hn * 4096 * 2);
    unsigned short* WeffB = (unsigned short*)alloc((size_t)Ln * Hn * 4096 * 2);
    float*          beffB = (float*)alloc((size_t)Ln * 49 * 4);
    unsigned short* xA    = (unsigned short*)alloc((size_t)Bn * Pn * 64 * 2);
    unsigned short* xB    = (unsigned short*)alloc((size_t)Bn * Pn * 64 * 2);
    float*          pooled = (float*)alloc((size_t)Bn * 49 * 4);

    const size_t per_b = 4 * ((size_t)Hn * Pn * 64 * 2);   // Q + K + Vt + AO bf16
    size_t fixed = (off + 255) & ~(size_t)255;
    int Bc = Bn;
    while (Bc > 8 && fixed + (size_t)Bc * per_b + 4096 > ws_size) Bc >>= 1;

    unsigned short* Qb  = (unsigned short*)alloc((size_t)Bc * Hn * Pn * 64 * 2);
    unsigned short* Kb  = (unsigned short*)alloc((size_t)Bc * Hn * Pn * 64 * 2);
    unsigned short* Vtb = (unsigned short*)alloc((size_t)Bc * Hn * Pn * 64 * 2);
    unsigned short* AOb = (unsigned short*)alloc((size_t)Bc * Hn * Pn * 64 * 2);

    prep_wqkv_kernel<<<(Ln * 3 * Hn * 4096 + 255) / 256, 256, 0, stream>>>(Wq, Wk, Wv, WqkvB);
    prep_weff_kernel<<<(Ln * Hn * 4096 + Ln * 49 + 255) / 256, 256, 0, stream>>>(Wh, bhp, Wout, WeffB, beffB);
    cast_x_kernel<<<(Bn * Pn * 64) / 256, 256, 0, stream>>>(emb, xA);

    unsigned short* cur = xA;
    unsigned short* nxt = xB;
    for (int l = 0; l < Ln; ++l) {
        const unsigned short* Wqkv_l = WqkvB + (size_t)l * 3 * Hn * 4096;
        const unsigned short* Weff_l = WeffB + (size_t)l * Hn * 4096;
        const float* beff_l = beffB + (size_t)l * 49;
        const float* bq_l = bq + (size_t)l * Hn * 49;
        const float* bk_l = bk + (size_t)l * Hn * 49;
        const float* bv_l = bv + (size_t)l * Hn * 49;

        for (int b0 = 0; b0 < Bn; b0 += Bc) {
            qkv_mfma_kernel<<<Bc * 8, 256, 0, stream>>>(cur, Wqkv_l, bq_l, bk_l, bv_l,
                                                        Qb, Kb, Vtb, b0, Bc);
            attn_head_kernel<<<Bc * 64, 128, 0, stream>>>(Qb, Kb, Vtb, AOb, Bc);
            outproj_mfma_kernel<<<Bc * 8, 256, 0, stream>>>(AOb, Weff_l, beff_l, nxt, b0, Bc);
        }
        unsigned short* tmp = cur; cur = nxt; nxt = tmp;
    }

    pool_kernel<<<Bn, 256, 0, stream>>>(cur, pooled);
    head_kernel<<<1, 64, 0, stream>>>(pooled, labels, W1, b1, W2, b2, out);
}